// Round 9
// baseline (186.528 us; speedup 1.0000x reference)
//
#include <hip/hip_runtime.h>

typedef __bf16 bf16_t;
typedef __bf16 bf16x8 __attribute__((ext_vector_type(8)));
typedef __bf16 bf16x4 __attribute__((ext_vector_type(4)));
typedef float f32x4 __attribute__((ext_vector_type(4)));
typedef unsigned short u16x8 __attribute__((ext_vector_type(8)));

#define AS1C(p) ((const __attribute__((address_space(1))) void*)(p))
#define AS3(p) ((__attribute__((address_space(3))) void*)(p))
#define MM(a, b, c) __builtin_amdgcn_mfma_f32_16x16x32_bf16(a, b, c, 0, 0, 0)

__device__ __forceinline__ unsigned short f2b_rne(float f) {
  union { float f; unsigned u; } x; x.f = f;
  unsigned u = x.u;
  u += 0x7fffu + ((u >> 16) & 1u);
  return (unsigned short)(u >> 16);
}

__device__ __forceinline__ float fast_exp2(float x) {
  return __builtin_amdgcn_exp2f(x);
}

// ---------------- cast f32 -> bf16 (vectorized, 8 elts/thread) ----------------
__global__ __launch_bounds__(256) void cast_f32_bf16(const float* __restrict__ in,
                                                     unsigned short* __restrict__ out,
                                                     int n) {
  int i = (blockIdx.x * 256 + threadIdx.x) * 8;
  if (i >= n) return;
  const float4* p = reinterpret_cast<const float4*>(in + i);
  float4 a = p[0], b = p[1];
  u16x8 o;
  o[0] = f2b_rne(a.x); o[1] = f2b_rne(a.y); o[2] = f2b_rne(a.z); o[3] = f2b_rne(a.w);
  o[4] = f2b_rne(b.x); o[5] = f2b_rne(b.y); o[6] = f2b_rne(b.z); o[7] = f2b_rne(b.w);
  *reinterpret_cast<u16x8*>(out + i) = o;
}

// four 1024x1024 weight casts in one launch; out slots contiguous (2 MB apart)
__global__ __launch_bounds__(256) void cast_w4(const float* __restrict__ w0,
                                               const float* __restrict__ w1,
                                               const float* __restrict__ w2,
                                               const float* __restrict__ w3,
                                               unsigned short* __restrict__ out) {
  const float* in = (blockIdx.y == 0) ? w0 : (blockIdx.y == 1) ? w1
                  : (blockIdx.y == 2) ? w2 : w3;
  int i = (blockIdx.x * 256 + threadIdx.x) * 8;
  unsigned short* o = out + (size_t)blockIdx.y * (1024u * 1024u);
  const float4* p = reinterpret_cast<const float4*>(in + i);
  float4 a = p[0], b = p[1];
  u16x8 v;
  v[0] = f2b_rne(a.x); v[1] = f2b_rne(a.y); v[2] = f2b_rne(a.z); v[3] = f2b_rne(a.w);
  v[4] = f2b_rne(b.x); v[5] = f2b_rne(b.y); v[6] = f2b_rne(b.z); v[7] = f2b_rne(b.w);
  *reinterpret_cast<u16x8*>(o + i) = v;
}

// ============ 128x256 / BK=64 GEMM, 3-buffer counted-vmcnt pipeline (round-8, unchanged) ====
template <int OUT_F32>
__global__ __launch_bounds__(512, 2) void gemm4(const bf16_t* __restrict__ A,
                                                const bf16_t* __restrict__ Bm,
                                                void* __restrict__ C,
                                                int M, int N, int K, int lda,
                                                float scale, int qlim) {
  extern __shared__ bf16_t lds[];   // 3 x 24576 elems (A 8192 + B 16384)
  const int tid = threadIdx.x;
  const int w = tid >> 6, l = tid & 63;
  const int r = l & 15, kg = l >> 4;
  const int wm64 = (w >> 2) * 64, wn32 = (w & 3) * 32;
  const int w8 = w * 8;
  const int m0 = blockIdx.y * 128, n0 = blockIdx.x * 256;
  const bf16_t* aSrc = A + (size_t)(m0 + w8 + (l >> 3)) * lda + ((l & 7) ^ (l >> 3)) * 8;
  const bf16_t* bSrc = Bm + (size_t)(n0 + w8 + (l >> 3)) * K + ((l & 7) ^ (l >> 3)) * 8;
  const int acol0 = (kg ^ (r & 7)) * 8;
  const int acol1 = ((4 + kg) ^ (r & 7)) * 8;

  f32x4 acc[2][4][2] = {};

  auto STAGE = [&](bf16_t* sb, int kt) {
    const bf16_t* ak = aSrc + kt * 64;
    const bf16_t* bk = bSrc + kt * 64;
    __builtin_amdgcn_global_load_lds(AS1C(ak),                    AS3(sb + (w8) * 64), 16, 0, 0);
    __builtin_amdgcn_global_load_lds(AS1C(ak + (size_t)64 * lda), AS3(sb + (64 + w8) * 64), 16, 0, 0);
    __builtin_amdgcn_global_load_lds(AS1C(bk),                    AS3(sb + 8192 + (w8) * 64), 16, 0, 0);
    __builtin_amdgcn_global_load_lds(AS1C(bk + (size_t)64 * K),   AS3(sb + 8192 + (64 + w8) * 64), 16, 0, 0);
    __builtin_amdgcn_global_load_lds(AS1C(bk + (size_t)128 * K),  AS3(sb + 8192 + (128 + w8) * 64), 16, 0, 0);
    __builtin_amdgcn_global_load_lds(AS1C(bk + (size_t)192 * K),  AS3(sb + 8192 + (192 + w8) * 64), 16, 0, 0);
  };

  bf16_t* cur = lds;
  bf16_t* nxt = lds + 24576;
  bf16_t* stg = lds + 49152;

  STAGE(cur, 0);
  STAGE(nxt, 1);
  asm volatile("s_waitcnt vmcnt(6)" ::: "memory");
  __builtin_amdgcn_s_barrier();

  const int NT = K >> 6;
  for (int t = 0; t < NT; ++t) {
    bf16x8 AF[4][2], BF[2][2][2];
#pragma unroll
    for (int il = 0; il < 4; ++il) {
      const int ao = (wm64 + il * 16 + r) * 64;
      AF[il][0] = *reinterpret_cast<const bf16x8*>(cur + ao + acol0);
      AF[il][1] = *reinterpret_cast<const bf16x8*>(cur + ao + acol1);
    }
#pragma unroll
    for (int qb = 0; qb < 2; ++qb)
#pragma unroll
      for (int jl = 0; jl < 2; ++jl) {
        const int bo = 8192 + (qb * 128 + wn32 + jl * 16 + r) * 64;
        BF[qb][jl][0] = *reinterpret_cast<const bf16x8*>(cur + bo + acol0);
        BF[qb][jl][1] = *reinterpret_cast<const bf16x8*>(cur + bo + acol1);
      }
    const int kt = (t + 2 < NT) ? t + 2 : t;
    STAGE(stg, kt);
    asm volatile("s_waitcnt lgkmcnt(4)" ::: "memory");
    __builtin_amdgcn_sched_barrier(0);
    __builtin_amdgcn_s_setprio(1);
#pragma unroll
    for (int il = 0; il < 4; ++il)
#pragma unroll
      for (int jl = 0; jl < 2; ++jl)
        acc[0][il][jl] = MM(AF[il][1], BF[0][jl][1], MM(AF[il][0], BF[0][jl][0], acc[0][il][jl]));
    __builtin_amdgcn_s_setprio(0);
    asm volatile("s_waitcnt lgkmcnt(0)" ::: "memory");
    __builtin_amdgcn_sched_barrier(0);
    __builtin_amdgcn_s_setprio(1);
#pragma unroll
    for (int il = 0; il < 4; ++il)
#pragma unroll
      for (int jl = 0; jl < 2; ++jl)
        acc[1][il][jl] = MM(AF[il][1], BF[1][jl][1], MM(AF[il][0], BF[1][jl][0], acc[1][il][jl]));
    __builtin_amdgcn_s_setprio(0);
    asm volatile("s_waitcnt vmcnt(6)" ::: "memory");
    __builtin_amdgcn_s_barrier();
    bf16_t* tmp = cur; cur = nxt; nxt = stg; stg = tmp;
  }

#pragma unroll
  for (int qb = 0; qb < 2; ++qb)
#pragma unroll
    for (int il = 0; il < 4; ++il)
#pragma unroll
      for (int jl = 0; jl < 2; ++jl) {
        const int row0 = m0 + wm64 + il * 16 + kg * 4;
        const int col = n0 + qb * 128 + wn32 + jl * 16 + r;
        const float sc = (col < qlim) ? scale : 1.0f;
#pragma unroll
        for (int v = 0; v < 4; ++v) {
          float val = acc[qb][il][jl][v] * sc;
          size_t idx = (size_t)(row0 + v) * N + col;
          if (OUT_F32) reinterpret_cast<float*>(C)[idx] = val;
          else reinterpret_cast<unsigned short*>(C)[idx] = f2b_rne(val);
        }
      }
}

// ---------------- V transpose: qkv V-columns [B*S][3072](+2048) -> VT [B*H][64][2048] ----------------
__global__ __launch_bounds__(256) void transpose_v(const bf16_t* __restrict__ qkv,
                                                   bf16_t* __restrict__ vt) {
  __shared__ bf16_t Vs[64 * 72];
  const int t = threadIdx.x;
  const int s0 = blockIdx.x * 64;
  const int bh = blockIdx.y;
  const int b = bh >> 4, h = bh & 15;
  const size_t in_base = ((size_t)b * 2048 + s0) * 3072 + 2048 + h * 64;
#pragma unroll
  for (int c = 0; c < 2; ++c) {
    int chunk = c * 256 + t;
    int ss = chunk >> 3, dd = (chunk & 7) * 8;
    bf16x8 v = *reinterpret_cast<const bf16x8*>(qkv + in_base + (size_t)ss * 3072 + dd);
    *reinterpret_cast<bf16x8*>(Vs + ss * 72 + dd) = v;
  }
  __syncthreads();
  const size_t out_base = (size_t)bh * 64 * 2048 + s0;
#pragma unroll
  for (int c = 0; c < 2; ++c) {
    int chunk = c * 256 + t;
    int dd = chunk >> 3, ss = (chunk & 7) * 8;
    bf16x8 o;
#pragma unroll
    for (int j = 0; j < 8; ++j) o[j] = Vs[(ss + j) * 72 + dd];
    *reinterpret_cast<bf16x8*>(vt + out_base + (size_t)dd * 2048 + ss) = o;
  }
}

// ---------------- causal flash attention: deferred-PV pipeline (T15) ----------------
// At iteration t: QK(t) MFMAs, then PV(t-1) MFMAs (pending P in regs, V from buf^1 — still
// resident in the double buffer; the next barrier fences the overwrite) overlap the
// mask/max/exp/sum VALU of tile t.  Rescale(alpha_t) runs AFTER PV(t-1) (both in m_{t-1}
// scale -> order-correct).  The diagonal tile flushes its own PV immediately (its V buffer
// would be overwritten 2 tiles later).  Rest identical to round 6-8.
__global__ __launch_bounds__(512) void flash_attn(const bf16_t* __restrict__ QKV,
                                                  const bf16_t* __restrict__ VT,
                                                  unsigned short* __restrict__ O,
                                                  int ostride) {
  __shared__ bf16_t Ks[2][64 * 72];
  __shared__ bf16_t Vts[2][64 * 72];
  __shared__ bf16_t Pl[8][16 * 72];
  const int tid = threadIdx.x;
  const int lane = tid & 63, wave = tid >> 6;
  const int r = lane & 15, kg = lane >> 4;
  const int bh = blockIdx.x;           // XCD = bh % 8 (8 heads/XCD, K/V set = 4 MB = L2)
  const int pair = blockIdx.y;         // 0..7; block does q-tiles {pair, 15-pair} (uniform)
  const int b = bh >> 4, h = bh & 15;
  const size_t qkv_row0 = (size_t)b * 2048 * 3072;
  const int qcol = h * 64, kcol = 1024 + h * 64;
  const size_t vt_base = (size_t)bh * 64 * 2048;
  const size_t o_row0 = (size_t)b * 2048 * ostride;
  const int ocol = h * 64;
  const int srr = tid >> 3, scc = (tid & 7) * 8;

  for (int pass = 0; pass < 2; ++pass) {
    const int qt = pass ? (15 - pair) : pair;
    const int q0 = qt * 128;
    const int qrow = q0 + wave * 16 + r;
    const int tmax_w = (q0 + wave * 16 + 15) >> 6;  // wave's diagonal tile
    const int ntiles = qt * 2 + 2;

    const size_t qoff = qkv_row0 + (size_t)qrow * 3072 + qcol;
    bf16x8 qf0 = *reinterpret_cast<const bf16x8*>(QKV + qoff + kg * 8);
    bf16x8 qf1 = *reinterpret_cast<const bf16x8*>(QKV + qoff + 32 + kg * 8);

    f32x4 oacc[4] = {};
    float m_run = -3e30f, l_lane = 0.f;
    bf16x8 paP0 = {}, paP1 = {};   // pending P fragments (valid when t>0, t<=tmax_w)

    bf16x8 gk = *reinterpret_cast<const bf16x8*>(QKV + qkv_row0 + (size_t)srr * 3072 + kcol + scc);
    bf16x8 gv = *reinterpret_cast<const bf16x8*>(VT + vt_base + (size_t)srr * 2048 + scc);

    for (int t = 0; t < ntiles; ++t) {
      const int buf = t & 1;
      *reinterpret_cast<bf16x8*>(&Ks[buf][srr * 72 + scc]) = gk;
      *reinterpret_cast<bf16x8*>(&Vts[buf][srr * 72 + scc]) = gv;
      __syncthreads();
      if (t + 1 < ntiles) {
        const int kv1 = (t + 1) * 64;
        gk = *reinterpret_cast<const bf16x8*>(QKV + qkv_row0 + (size_t)(kv1 + srr) * 3072 + kcol + scc);
        gv = *reinterpret_cast<const bf16x8*>(VT + vt_base + (size_t)srr * 2048 + kv1 + scc);
      }
      if (t > tmax_w) continue;  // fully masked for this wave; PV already flushed at tmax_w

      const int kv0 = t * 64;
      // S^T = mfma(K, Q): out col = q (=r), row = k-local -> softmax is lane-local
      float vals[16];
      __builtin_amdgcn_s_setprio(1);
#pragma unroll
      for (int nt = 0; nt < 4; ++nt) {
        bf16x8 kf0 = *reinterpret_cast<const bf16x8*>(&Ks[buf][(nt * 16 + r) * 72 + kg * 8]);
        bf16x8 kf1 = *reinterpret_cast<const bf16x8*>(&Ks[buf][(nt * 16 + r) * 72 + 32 + kg * 8]);
        f32x4 s = {};
        s = MM(kf0, qf0, s);
        s = MM(kf1, qf1, s);
#pragma unroll
        for (int v = 0; v < 4; ++v) vals[nt * 4 + v] = s[v];
      }
      __builtin_amdgcn_s_setprio(0);

      // pending PV(t-1): independent of vals -> scheduler overlaps these MFMAs with the
      // mask/max/exp VALU below.  V(t-1) lives in buf^1 (double-buffered, barrier-fenced).
      if (t > 0) {
#pragma unroll
        for (int dt = 0; dt < 4; ++dt) {
          bf16x8 vb0 = *reinterpret_cast<const bf16x8*>(&Vts[buf ^ 1][(dt * 16 + r) * 72 + kg * 8]);
          bf16x8 vb1 = *reinterpret_cast<const bf16x8*>(&Vts[buf ^ 1][(dt * 16 + r) * 72 + 32 + kg * 8]);
          oacc[dt] = MM(paP0, vb0, oacc[dt]);
          oacc[dt] = MM(paP1, vb1, oacc[dt]);
        }
      }

      if (t == tmax_w) {  // diagonal tile: mask k > q
#pragma unroll
        for (int nt = 0; nt < 4; ++nt)
#pragma unroll
          for (int v = 0; v < 4; ++v)
            if (kv0 + nt * 16 + kg * 4 + v > qrow) vals[nt * 4 + v] = -3e30f;
      }
      float a0 = fmaxf(fmaxf(vals[0], vals[1]), vals[2]);
      float a1 = fmaxf(fmaxf(vals[3], vals[4]), vals[5]);
      float a2 = fmaxf(fmaxf(vals[6], vals[7]), vals[8]);
      float a3 = fmaxf(fmaxf(vals[9], vals[10]), vals[11]);
      float a4 = fmaxf(fmaxf(vals[12], vals[13]), vals[14]);
      float pmax = fmaxf(fmaxf(fmaxf(a0, a1), fmaxf(a2, a3)), fmaxf(a4, vals[15]));
      // defer-max: rescale only when some lane's partial grew past THR=8 (P <= 2^8)
      if (!__all(pmax <= m_run + 8.0f)) {
        pmax = fmaxf(pmax, __shfl_xor(pmax, 16));
        pmax = fmaxf(pmax, __shfl_xor(pmax, 32));
        const float m_new = fmaxf(m_run, pmax);
        const float alpha = fast_exp2(m_run - m_new);
        l_lane *= alpha;
        f32x4 al;
#pragma unroll
        for (int v = 0; v < 4; ++v) al[v] = __shfl(alpha, kg * 4 + v);
#pragma unroll
        for (int dt = 0; dt < 4; ++dt)
#pragma unroll
          for (int v = 0; v < 4; ++v) oacc[dt][v] *= al[v];
        m_run = m_new;
      }
      // exp + 4-way partial-sum tree (short dep chains)
      float ps0 = 0.f, ps1 = 0.f, ps2 = 0.f, ps3 = 0.f;
#pragma unroll
      for (int ii = 0; ii < 4; ++ii) {
        float p0 = fast_exp2(vals[ii] - m_run);
        float p1 = fast_exp2(vals[4 + ii] - m_run);
        float p2 = fast_exp2(vals[8 + ii] - m_run);
        float p3 = fast_exp2(vals[12 + ii] - m_run);
        vals[ii] = p0; vals[4 + ii] = p1; vals[8 + ii] = p2; vals[12 + ii] = p3;
        ps0 += p0; ps1 += p1; ps2 += p2; ps3 += p3;
      }
      l_lane += (ps0 + ps1) + (ps2 + ps3);

      // pack P(t) -> Pl (A-frag layout) -> pending fragments for next iteration
#pragma unroll
      for (int nt = 0; nt < 4; ++nt) {
        bf16x4 pb;
#pragma unroll
        for (int v = 0; v < 4; ++v) pb[v] = (bf16_t)vals[nt * 4 + v];
        *reinterpret_cast<bf16x4*>(&Pl[wave][r * 72 + nt * 16 + kg * 4]) = pb;
      }
      paP0 = *reinterpret_cast<const bf16x8*>(&Pl[wave][r * 72 + kg * 8]);
      paP1 = *reinterpret_cast<const bf16x8*>(&Pl[wave][r * 72 + 32 + kg * 8]);

      if (t == tmax_w) {  // last tile for this wave: flush immediately (V(t) in buf)
        __builtin_amdgcn_s_setprio(1);
#pragma unroll
        for (int dt = 0; dt < 4; ++dt) {
          bf16x8 vb0 = *reinterpret_cast<const bf16x8*>(&Vts[buf][(dt * 16 + r) * 72 + kg * 8]);
          bf16x8 vb1 = *reinterpret_cast<const bf16x8*>(&Vts[buf][(dt * 16 + r) * 72 + 32 + kg * 8]);
          oacc[dt] = MM(paP0, vb0, oacc[dt]);
          oacc[dt] = MM(paP1, vb1, oacc[dt]);
        }
        __builtin_amdgcn_s_setprio(0);
      }
    }

    float l_row = l_lane;
    l_row += __shfl_xor(l_row, 16);
    l_row += __shfl_xor(l_row, 32);
    const float linv = 1.0f / l_row;
    f32x4 il;
#pragma unroll
    for (int v = 0; v < 4; ++v) il[v] = __shfl(linv, kg * 4 + v);
    const size_t orow0 = o_row0 + (size_t)(q0 + wave * 16) * ostride + ocol;
#pragma unroll
    for (int dt = 0; dt < 4; ++dt) {
      const int d = dt * 16 + r;
#pragma unroll
      for (int v = 0; v < 4; ++v)
        O[orow0 + (size_t)(kg * 4 + v) * ostride + d] = f2b_rne(oacc[dt][v] * il[v]);
    }
  }
}

// ---------------- launcher ----------------
extern "C" void kernel_launch(void* const* d_in, const int* in_sizes, int n_in,
                              void* d_out, int out_size, void* d_ws, size_t ws_size,
                              hipStream_t stream) {
  const float* x  = (const float*)d_in[0];
  const float* Wq = (const float*)d_in[1];
  const float* Wk = (const float*)d_in[2];
  const float* Wv = (const float*)d_in[3];
  const float* Wo = (const float*)d_in[4];

  char* ws = (char*)d_ws;
  bf16_t* xb  = (bf16_t*)(ws);
  bf16_t* wqb = (bf16_t*)(ws + (16u << 20));
  bf16_t* wob = (bf16_t*)(ws + (22u << 20));
  bf16_t* qkv = (bf16_t*)(ws + (24u << 20));
  bf16_t* vt  = (bf16_t*)(ws);

  hipFuncSetAttribute(reinterpret_cast<const void*>(&gemm4<0>),
                      hipFuncAttributeMaxDynamicSharedMemorySize, 147456);
  hipFuncSetAttribute(reinterpret_cast<const void*>(&gemm4<1>),
                      hipFuncAttributeMaxDynamicSharedMemorySize, 147456);

  const int NX = 4 * 2048 * 1024;
  cast_f32_bf16<<<NX / 2048, 256, 0, stream>>>(x, (unsigned short*)xb, NX);
  cast_w4<<<dim3(512, 4), 256, 0, stream>>>(Wq, Wk, Wv, Wo, (unsigned short*)wqb);

  // fused QKV projection; Q cols scaled by 1/sqrt(dk)*log2(e) (exp2-domain softmax)
  gemm4<0><<<dim3(3072 / 256, 8192 / 128), 512, 147456, stream>>>(
      xb, wqb, qkv, 8192, 3072, 1024, 1024, 0.18033688011112042f, 1024);

  transpose_v<<<dim3(2048 / 64, 64), 256, 0, stream>>>(qkv, vt);

  flash_attn<<<dim3(64, 8), 512, 0, stream>>>(qkv, vt, (unsigned short*)qkv, 3072);

  gemm4<1><<<dim3(1024 / 256, 8192 / 128), 512, 147456, stream>>>(
      qkv, wob, d_out, 8192, 1024, 1024, 3072, 1.0f, 0);
}

// Round 10
// 180.911 us; speedup vs baseline: 1.0310x; 1.0310x over previous
//
#include <hip/hip_runtime.h>

typedef __bf16 bf16_t;
typedef __bf16 bf16x8 __attribute__((ext_vector_type(8)));
typedef __bf16 bf16x4 __attribute__((ext_vector_type(4)));
typedef float f32x4 __attribute__((ext_vector_type(4)));
typedef unsigned short u16x8 __attribute__((ext_vector_type(8)));

#define AS1C(p) ((const __attribute__((address_space(1))) void*)(p))
#define AS3(p) ((__attribute__((address_space(3))) void*)(p))
#define MM(a, b, c) __builtin_amdgcn_mfma_f32_16x16x32_bf16(a, b, c, 0, 0, 0)

__device__ __forceinline__ unsigned short f2b_rne(float f) {
  union { float f; unsigned u; } x; x.f = f;
  unsigned u = x.u;
  u += 0x7fffu + ((u >> 16) & 1u);
  return (unsigned short)(u >> 16);
}

__device__ __forceinline__ float fast_exp2(float x) {
  return __builtin_amdgcn_exp2f(x);
}

// ---------------- cast f32 -> bf16 (vectorized, 8 elts/thread) ----------------
__global__ __launch_bounds__(256) void cast_f32_bf16(const float* __restrict__ in,
                                                     unsigned short* __restrict__ out,
                                                     int n) {
  int i = (blockIdx.x * 256 + threadIdx.x) * 8;
  if (i >= n) return;
  const float4* p = reinterpret_cast<const float4*>(in + i);
  float4 a = p[0], b = p[1];
  u16x8 o;
  o[0] = f2b_rne(a.x); o[1] = f2b_rne(a.y); o[2] = f2b_rne(a.z); o[3] = f2b_rne(a.w);
  o[4] = f2b_rne(b.x); o[5] = f2b_rne(b.y); o[6] = f2b_rne(b.z); o[7] = f2b_rne(b.w);
  *reinterpret_cast<u16x8*>(out + i) = o;
}

// four 1024x1024 weight casts in one launch; out slots contiguous (2 MB apart)
__global__ __launch_bounds__(256) void cast_w4(const float* __restrict__ w0,
                                               const float* __restrict__ w1,
                                               const float* __restrict__ w2,
                                               const float* __restrict__ w3,
                                               unsigned short* __restrict__ out) {
  const float* in = (blockIdx.y == 0) ? w0 : (blockIdx.y == 1) ? w1
                  : (blockIdx.y == 2) ? w2 : w3;
  int i = (blockIdx.x * 256 + threadIdx.x) * 8;
  unsigned short* o = out + (size_t)blockIdx.y * (1024u * 1024u);
  const float4* p = reinterpret_cast<const float4*>(in + i);
  float4 a = p[0], b = p[1];
  u16x8 v;
  v[0] = f2b_rne(a.x); v[1] = f2b_rne(a.y); v[2] = f2b_rne(a.z); v[3] = f2b_rne(a.w);
  v[4] = f2b_rne(b.x); v[5] = f2b_rne(b.y); v[6] = f2b_rne(b.z); v[7] = f2b_rne(b.w);
  *reinterpret_cast<u16x8*>(o + i) = v;
}

// ============ 128x256 / BK=32 GEMM, 3-buffer counted-vmcnt, 2 blocks/CU ============
// C[M,N] = A[M,K] (row stride lda) * B[N,K]^T.  512 thr = 8 waves (2M x 4N); per-wave out
// 64x64 (acc = 64 VGPR -> fits 128-VGPR budget at 4 waves/SIMD = 2 blocks/CU).
// LDS = 3 bufs x (A 128x32 + B 256x32) bf16 = 72 KiB -> 2 blocks/CU (144 KiB).
// Pipeline (gemm4-verified logic at BK=32): tile T in buf T%3; stage(T+2) issues during T;
// vmcnt(3) at end of T retires stage(T+1)'s 3 loads while stage(T+2) stays in flight.
// At BK=32 (row = 64 B = 16 banks) both the staging writes and frag reads are naturally
// bank-balanced -> no swizzle needed.
template <int OUT_F32>
__global__ __launch_bounds__(512, 4) void gemmk(const bf16_t* __restrict__ A,
                                                const bf16_t* __restrict__ Bm,
                                                void* __restrict__ C,
                                                int M, int N, int K, int lda,
                                                float scale, int qlim) {
  extern __shared__ bf16_t lds[];   // 3 x 12288 elems (A 4096 + B 8192) = 73728 B
  const int tid = threadIdx.x;
  const int w = tid >> 6, l = tid & 63;
  const int r = l & 15, kg = l >> 4;
  const int wm = (w >> 2) * 64;         // A-row group
  const int wn = (w & 3) * 64;          // B-col group
  const int m0 = blockIdx.y * 128, n0 = blockIdx.x * 256;
  // staging: 512 thr x 16B = 8 KB = one 128x32 bf16 panel per call (linear dest = row-major)
  const int srow = w * 16 + (l >> 2);   // 0..127
  const int scol = (l & 3) * 8;
  const bf16_t* aS = A + (size_t)(m0 + srow) * lda + scol;
  const bf16_t* bS = Bm + (size_t)(n0 + srow) * K + scol;

  f32x4 acc[4][4] = {};

  auto STAGE = [&](bf16_t* sb, int kt) {
    __builtin_amdgcn_global_load_lds(AS1C(aS + kt * 32), AS3(sb + w * 512), 16, 0, 0);
    __builtin_amdgcn_global_load_lds(AS1C(bS + kt * 32), AS3(sb + 4096 + w * 512), 16, 0, 0);
    __builtin_amdgcn_global_load_lds(AS1C(bS + (size_t)128 * K + kt * 32),
                                     AS3(sb + 8192 + w * 512), 16, 0, 0);
  };

  bf16_t* cur = lds;
  bf16_t* nxt = lds + 12288;
  bf16_t* stg = lds + 24576;

  STAGE(cur, 0);
  STAGE(nxt, 1);
  asm volatile("s_waitcnt vmcnt(3)" ::: "memory");   // tile 0 landed; tile 1 in flight
  __builtin_amdgcn_s_barrier();

  const int NT = K >> 5;
  for (int t = 0; t < NT; ++t) {
    bf16x8 AF[4], BF[4];
#pragma unroll
    for (int il = 0; il < 4; ++il)
      AF[il] = *reinterpret_cast<const bf16x8*>(cur + (wm + il * 16 + r) * 32 + kg * 8);
#pragma unroll
    for (int jl = 0; jl < 4; ++jl)
      BF[jl] = *reinterpret_cast<const bf16x8*>(cur + 4096 + (wn + jl * 16 + r) * 32 + kg * 8);
    const int kt = (t + 2 < NT) ? t + 2 : t;   // tail: benign re-stage into unused buf
    STAGE(stg, kt);
    asm volatile("s_waitcnt lgkmcnt(2)" ::: "memory");   // A + B jl0,jl1 resident
    __builtin_amdgcn_sched_barrier(0);
    __builtin_amdgcn_s_setprio(1);
#pragma unroll
    for (int il = 0; il < 4; ++il)
#pragma unroll
      for (int jl = 0; jl < 2; ++jl)
        acc[il][jl] = MM(AF[il], BF[jl], acc[il][jl]);
    __builtin_amdgcn_s_setprio(0);
    asm volatile("s_waitcnt lgkmcnt(0)" ::: "memory");   // B jl2,jl3 resident
    __builtin_amdgcn_sched_barrier(0);
    __builtin_amdgcn_s_setprio(1);
#pragma unroll
    for (int il = 0; il < 4; ++il)
#pragma unroll
      for (int jl = 2; jl < 4; ++jl)
        acc[il][jl] = MM(AF[il], BF[jl], acc[il][jl]);
    __builtin_amdgcn_s_setprio(0);
    asm volatile("s_waitcnt vmcnt(3)" ::: "memory");     // next tile's loads landed
    __builtin_amdgcn_s_barrier();
    bf16_t* tmp = cur; cur = nxt; nxt = stg; stg = tmp;
  }

  // epilogue: rows m0 + wm + il*16 + kg*4 + v; cols n0 + wn + jl*16 + r
#pragma unroll
  for (int il = 0; il < 4; ++il)
#pragma unroll
    for (int jl = 0; jl < 4; ++jl) {
      const int row0 = m0 + wm + il * 16 + kg * 4;
      const int col = n0 + wn + jl * 16 + r;
      const float sc = (col < qlim) ? scale : 1.0f;
#pragma unroll
      for (int v = 0; v < 4; ++v) {
        float val = acc[il][jl][v] * sc;
        size_t idx = (size_t)(row0 + v) * N + col;
        if (OUT_F32) reinterpret_cast<float*>(C)[idx] = val;
        else reinterpret_cast<unsigned short*>(C)[idx] = f2b_rne(val);
      }
    }
}

// ---------------- V transpose: qkv V-columns [B*S][3072](+2048) -> VT [B*H][64][2048] ----------------
__global__ __launch_bounds__(256) void transpose_v(const bf16_t* __restrict__ qkv,
                                                   bf16_t* __restrict__ vt) {
  __shared__ bf16_t Vs[64 * 72];
  const int t = threadIdx.x;
  const int s0 = blockIdx.x * 64;
  const int bh = blockIdx.y;
  const int b = bh >> 4, h = bh & 15;
  const size_t in_base = ((size_t)b * 2048 + s0) * 3072 + 2048 + h * 64;
#pragma unroll
  for (int c = 0; c < 2; ++c) {
    int chunk = c * 256 + t;
    int ss = chunk >> 3, dd = (chunk & 7) * 8;
    bf16x8 v = *reinterpret_cast<const bf16x8*>(qkv + in_base + (size_t)ss * 3072 + dd);
    *reinterpret_cast<bf16x8*>(Vs + ss * 72 + dd) = v;
  }
  __syncthreads();
  const size_t out_base = (size_t)bh * 64 * 2048 + s0;
#pragma unroll
  for (int c = 0; c < 2; ++c) {
    int chunk = c * 256 + t;
    int dd = chunk >> 3, ss = (chunk & 7) * 8;
    bf16x8 o;
#pragma unroll
    for (int j = 0; j < 8; ++j) o[j] = Vs[(ss + j) * 72 + dd];
    *reinterpret_cast<bf16x8*>(vt + out_base + (size_t)dd * 2048 + ss) = o;
  }
}

// ---------------- causal flash attention (round-8 body; 1 q-tile/block, 3 blocks/CU) ----------
// grid (64 bh, 16 qt-slot); qt = 15 - blockIdx.y -> heavy tiles dispatch first (LPT);
// XCD = linear_id % 8 = bh % 8 (8 heads/XCD = 4 MB K/V set = one L2).  LDS 53 KiB
// (Pl stride 68) -> 3 blocks/CU = 24 waves; 768 resident + 256 queued refill dynamically.
__global__ __launch_bounds__(512, 6) void flash_attn(const bf16_t* __restrict__ QKV,
                                                     const bf16_t* __restrict__ VT,
                                                     unsigned short* __restrict__ O,
                                                     int ostride) {
  __shared__ bf16_t Ks[2][64 * 72];
  __shared__ bf16_t Vts[2][64 * 72];
  __shared__ bf16_t Pl[8][16 * 68];
  const int tid = threadIdx.x;
  const int lane = tid & 63, wave = tid >> 6;
  const int r = lane & 15, kg = lane >> 4;
  const int bh = blockIdx.x;
  const int qt = 15 - (int)blockIdx.y;
  const int b = bh >> 4, h = bh & 15;
  const size_t qkv_row0 = (size_t)b * 2048 * 3072;
  const int qcol = h * 64, kcol = 1024 + h * 64;
  const size_t vt_base = (size_t)bh * 64 * 2048;
  const size_t o_row0 = (size_t)b * 2048 * ostride;
  const int ocol = h * 64;
  const int srr = tid >> 3, scc = (tid & 7) * 8;

  const int q0 = qt * 128;
  const int qrow = q0 + wave * 16 + r;
  const int tmax_w = (q0 + wave * 16 + 15) >> 6;
  const int ntiles = qt * 2 + 2;

  const size_t qoff = qkv_row0 + (size_t)qrow * 3072 + qcol;
  bf16x8 qf0 = *reinterpret_cast<const bf16x8*>(QKV + qoff + kg * 8);
  bf16x8 qf1 = *reinterpret_cast<const bf16x8*>(QKV + qoff + 32 + kg * 8);

  f32x4 oacc[4] = {};
  float m_run = -3e30f, l_lane = 0.f;

  bf16x8 gk = *reinterpret_cast<const bf16x8*>(QKV + qkv_row0 + (size_t)srr * 3072 + kcol + scc);
  bf16x8 gv = *reinterpret_cast<const bf16x8*>(VT + vt_base + (size_t)srr * 2048 + scc);

  for (int t = 0; t < ntiles; ++t) {
    const int buf = t & 1;
    *reinterpret_cast<bf16x8*>(&Ks[buf][srr * 72 + scc]) = gk;
    *reinterpret_cast<bf16x8*>(&Vts[buf][srr * 72 + scc]) = gv;
    __syncthreads();
    if (t + 1 < ntiles) {
      const int kv1 = (t + 1) * 64;
      gk = *reinterpret_cast<const bf16x8*>(QKV + qkv_row0 + (size_t)(kv1 + srr) * 3072 + kcol + scc);
      gv = *reinterpret_cast<const bf16x8*>(VT + vt_base + (size_t)srr * 2048 + kv1 + scc);
    }
    if (t > tmax_w) continue;

    const int kv0 = t * 64;
    float vals[16];
#pragma unroll
    for (int nt = 0; nt < 4; ++nt) {
      bf16x8 kf0 = *reinterpret_cast<const bf16x8*>(&Ks[buf][(nt * 16 + r) * 72 + kg * 8]);
      bf16x8 kf1 = *reinterpret_cast<const bf16x8*>(&Ks[buf][(nt * 16 + r) * 72 + 32 + kg * 8]);
      f32x4 s = {};
      __builtin_amdgcn_s_setprio(1);
      s = MM(kf0, qf0, s);
      s = MM(kf1, qf1, s);
      __builtin_amdgcn_s_setprio(0);
#pragma unroll
      for (int v = 0; v < 4; ++v) vals[nt * 4 + v] = s[v];
    }
    if (t == tmax_w) {
#pragma unroll
      for (int nt = 0; nt < 4; ++nt)
#pragma unroll
        for (int v = 0; v < 4; ++v)
          if (kv0 + nt * 16 + kg * 4 + v > qrow) vals[nt * 4 + v] = -3e30f;
    }
    float a0 = fmaxf(fmaxf(vals[0], vals[1]), vals[2]);
    float a1 = fmaxf(fmaxf(vals[3], vals[4]), vals[5]);
    float a2 = fmaxf(fmaxf(vals[6], vals[7]), vals[8]);
    float a3 = fmaxf(fmaxf(vals[9], vals[10]), vals[11]);
    float a4 = fmaxf(fmaxf(vals[12], vals[13]), vals[14]);
    float pmax = fmaxf(fmaxf(fmaxf(a0, a1), fmaxf(a2, a3)), fmaxf(a4, vals[15]));
    if (!__all(pmax <= m_run + 8.0f)) {
      pmax = fmaxf(pmax, __shfl_xor(pmax, 16));
      pmax = fmaxf(pmax, __shfl_xor(pmax, 32));
      const float m_new = fmaxf(m_run, pmax);
      const float alpha = fast_exp2(m_run - m_new);
      l_lane *= alpha;
      f32x4 al;
#pragma unroll
      for (int v = 0; v < 4; ++v) al[v] = __shfl(alpha, kg * 4 + v);
#pragma unroll
      for (int dt = 0; dt < 4; ++dt)
#pragma unroll
        for (int v = 0; v < 4; ++v) oacc[dt][v] *= al[v];
      m_run = m_new;
    }
#pragma unroll
    for (int ii = 0; ii < 16; ++ii) {
      float p = fast_exp2(vals[ii] - m_run);
      vals[ii] = p;
      l_lane += p;
    }
#pragma unroll
    for (int nt = 0; nt < 4; ++nt) {
      bf16x4 pb;
#pragma unroll
      for (int v = 0; v < 4; ++v) pb[v] = (bf16_t)vals[nt * 4 + v];
      *reinterpret_cast<bf16x4*>(&Pl[wave][r * 68 + nt * 16 + kg * 4]) = pb;
    }
    bf16x8 pa0 = *reinterpret_cast<const bf16x8*>(&Pl[wave][r * 68 + kg * 8]);
    bf16x8 pa1 = *reinterpret_cast<const bf16x8*>(&Pl[wave][r * 68 + 32 + kg * 8]);
#pragma unroll
    for (int dt = 0; dt < 4; ++dt) {
      bf16x8 vb0 = *reinterpret_cast<const bf16x8*>(&Vts[buf][(dt * 16 + r) * 72 + kg * 8]);
      bf16x8 vb1 = *reinterpret_cast<const bf16x8*>(&Vts[buf][(dt * 16 + r) * 72 + 32 + kg * 8]);
      __builtin_amdgcn_s_setprio(1);
      oacc[dt] = MM(pa0, vb0, oacc[dt]);
      oacc[dt] = MM(pa1, vb1, oacc[dt]);
      __builtin_amdgcn_s_setprio(0);
    }
  }

  float l_row = l_lane;
  l_row += __shfl_xor(l_row, 16);
  l_row += __shfl_xor(l_row, 32);
  const float linv = 1.0f / l_row;
  f32x4 il;
#pragma unroll
  for (int v = 0; v < 4; ++v) il[v] = __shfl(linv, kg * 4 + v);
  const size_t orow0 = o_row0 + (size_t)(q0 + wave * 16) * ostride + ocol;
#pragma unroll
  for (int dt = 0; dt < 4; ++dt) {
    const int d = dt * 16 + r;
#pragma unroll
    for (int v = 0; v < 4; ++v)
      O[orow0 + (size_t)(kg * 4 + v) * ostride + d] = f2b_rne(oacc[dt][v] * il[v]);
  }
}

// ---------------- launcher ----------------
extern "C" void kernel_launch(void* const* d_in, const int* in_sizes, int n_in,
                              void* d_out, int out_size, void* d_ws, size_t ws_size,
                              hipStream_t stream) {
  const float* x  = (const float*)d_in[0];
  const float* Wq = (const float*)d_in[1];
  const float* Wk = (const float*)d_in[2];
  const float* Wv = (const float*)d_in[3];
  const float* Wo = (const float*)d_in[4];

  // ws layout (72 MB peak):
  //  phase 1 (casts+QKV GEMM): xb [0,16) | wqb|wkb|wvb|wob [16,24) | qkv [24,72)
  //  phase 2 (transpose/flash): vt [0,16) (xb dead); flash writes O in-place into qkv Q cols
  //  phase 3 (Wo GEMM): qkv as A (lda=3072), wob -> d_out
  char* ws = (char*)d_ws;
  bf16_t* xb  = (bf16_t*)(ws);
  bf16_t* wqb = (bf16_t*)(ws + (16u << 20));
  bf16_t* wob = (bf16_t*)(ws + (22u << 20));
  bf16_t* qkv = (bf16_t*)(ws + (24u << 20));
  bf16_t* vt  = (bf16_t*)(ws);

  hipFuncSetAttribute(reinterpret_cast<const void*>(&gemmk<0>),
                      hipFuncAttributeMaxDynamicSharedMemorySize, 73728);
  hipFuncSetAttribute(reinterpret_cast<const void*>(&gemmk<1>),
                      hipFuncAttributeMaxDynamicSharedMemorySize, 73728);

  const int NX = 4 * 2048 * 1024;
  cast_f32_bf16<<<NX / 2048, 256, 0, stream>>>(x, (unsigned short*)xb, NX);
  cast_w4<<<dim3(512, 4), 256, 0, stream>>>(Wq, Wk, Wv, Wo, (unsigned short*)wqb);

  // fused QKV projection: grid (12, 64) = 768 blocks at 2/CU (work-conserving refill)
  gemmk<0><<<dim3(3072 / 256, 8192 / 128), 512, 73728, stream>>>(
      xb, wqb, qkv, 8192, 3072, 1024, 1024, 0.18033688011112042f, 1024);

  transpose_v<<<dim3(2048 / 64, 64), 256, 0, stream>>>(qkv, vt);

  flash_attn<<<dim3(64, 16), 512, 0, stream>>>(qkv, vt, (unsigned short*)qkv, 3072);

  // output projection: grid (4, 64) = 256 blocks
  gemmk<1><<<dim3(1024 / 256, 8192 / 128), 512, 73728, stream>>>(
      qkv, wob, d_out, 8192, 1024, 1024, 3072, 1.0f, 0);
}

// Round 11
// 172.473 us; speedup vs baseline: 1.0815x; 1.0489x over previous
//
#include <hip/hip_runtime.h>

typedef __bf16 bf16_t;
typedef __bf16 bf16x8 __attribute__((ext_vector_type(8)));
typedef __bf16 bf16x4 __attribute__((ext_vector_type(4)));
typedef float f32x4 __attribute__((ext_vector_type(4)));
typedef unsigned short u16x8 __attribute__((ext_vector_type(8)));

#define AS1C(p) ((const __attribute__((address_space(1))) void*)(p))
#define AS3(p) ((__attribute__((address_space(3))) void*)(p))
#define MM(a, b, c) __builtin_amdgcn_mfma_f32_16x16x32_bf16(a, b, c, 0, 0, 0)

__device__ __forceinline__ unsigned short f2b_rne(float f) {
  union { float f; unsigned u; } x; x.f = f;
  unsigned u = x.u;
  u += 0x7fffu + ((u >> 16) & 1u);
  return (unsigned short)(u >> 16);
}

__device__ __forceinline__ float fast_exp2(float x) {
  return __builtin_amdgcn_exp2f(x);
}

// ---------------- cast f32 -> bf16 (vectorized, 8 elts/thread) ----------------
__global__ __launch_bounds__(256) void cast_f32_bf16(const float* __restrict__ in,
                                                     unsigned short* __restrict__ out,
                                                     int n) {
  int i = (blockIdx.x * 256 + threadIdx.x) * 8;
  if (i >= n) return;
  const float4* p = reinterpret_cast<const float4*>(in + i);
  float4 a = p[0], b = p[1];
  u16x8 o;
  o[0] = f2b_rne(a.x); o[1] = f2b_rne(a.y); o[2] = f2b_rne(a.z); o[3] = f2b_rne(a.w);
  o[4] = f2b_rne(b.x); o[5] = f2b_rne(b.y); o[6] = f2b_rne(b.z); o[7] = f2b_rne(b.w);
  *reinterpret_cast<u16x8*>(out + i) = o;
}

// four 1024x1024 weight casts in one launch; out slots contiguous (2 MB apart)
__global__ __launch_bounds__(256) void cast_w4(const float* __restrict__ w0,
                                               const float* __restrict__ w1,
                                               const float* __restrict__ w2,
                                               const float* __restrict__ w3,
                                               unsigned short* __restrict__ out) {
  const float* in = (blockIdx.y == 0) ? w0 : (blockIdx.y == 1) ? w1
                  : (blockIdx.y == 2) ? w2 : w3;
  int i = (blockIdx.x * 256 + threadIdx.x) * 8;
  unsigned short* o = out + (size_t)blockIdx.y * (1024u * 1024u);
  const float4* p = reinterpret_cast<const float4*>(in + i);
  float4 a = p[0], b = p[1];
  u16x8 v;
  v[0] = f2b_rne(a.x); v[1] = f2b_rne(a.y); v[2] = f2b_rne(a.z); v[3] = f2b_rne(a.w);
  v[4] = f2b_rne(b.x); v[5] = f2b_rne(b.y); v[6] = f2b_rne(b.z); v[7] = f2b_rne(b.w);
  *reinterpret_cast<u16x8*>(o + i) = v;
}

// ============ 128x256 / BK=32 GEMM, 3-buffer counted-vmcnt, 2 blocks/CU (round-10) ============
template <int OUT_F32>
__global__ __launch_bounds__(512, 4) void gemmk(const bf16_t* __restrict__ A,
                                                const bf16_t* __restrict__ Bm,
                                                void* __restrict__ C,
                                                int M, int N, int K, int lda,
                                                float scale, int qlim) {
  extern __shared__ bf16_t lds[];   // 3 x 12288 elems (A 4096 + B 8192) = 73728 B
  const int tid = threadIdx.x;
  const int w = tid >> 6, l = tid & 63;
  const int r = l & 15, kg = l >> 4;
  const int wm = (w >> 2) * 64;
  const int wn = (w & 3) * 64;
  const int m0 = blockIdx.y * 128, n0 = blockIdx.x * 256;
  const int srow = w * 16 + (l >> 2);
  const int scol = (l & 3) * 8;
  const bf16_t* aS = A + (size_t)(m0 + srow) * lda + scol;
  const bf16_t* bS = Bm + (size_t)(n0 + srow) * K + scol;

  f32x4 acc[4][4] = {};

  auto STAGE = [&](bf16_t* sb, int kt) {
    __builtin_amdgcn_global_load_lds(AS1C(aS + kt * 32), AS3(sb + w * 512), 16, 0, 0);
    __builtin_amdgcn_global_load_lds(AS1C(bS + kt * 32), AS3(sb + 4096 + w * 512), 16, 0, 0);
    __builtin_amdgcn_global_load_lds(AS1C(bS + (size_t)128 * K + kt * 32),
                                     AS3(sb + 8192 + w * 512), 16, 0, 0);
  };

  bf16_t* cur = lds;
  bf16_t* nxt = lds + 12288;
  bf16_t* stg = lds + 24576;

  STAGE(cur, 0);
  STAGE(nxt, 1);
  asm volatile("s_waitcnt vmcnt(3)" ::: "memory");
  __builtin_amdgcn_s_barrier();

  const int NT = K >> 5;
  for (int t = 0; t < NT; ++t) {
    bf16x8 AF[4], BF[4];
#pragma unroll
    for (int il = 0; il < 4; ++il)
      AF[il] = *reinterpret_cast<const bf16x8*>(cur + (wm + il * 16 + r) * 32 + kg * 8);
#pragma unroll
    for (int jl = 0; jl < 4; ++jl)
      BF[jl] = *reinterpret_cast<const bf16x8*>(cur + 4096 + (wn + jl * 16 + r) * 32 + kg * 8);
    const int kt = (t + 2 < NT) ? t + 2 : t;
    STAGE(stg, kt);
    asm volatile("s_waitcnt lgkmcnt(2)" ::: "memory");
    __builtin_amdgcn_sched_barrier(0);
    __builtin_amdgcn_s_setprio(1);
#pragma unroll
    for (int il = 0; il < 4; ++il)
#pragma unroll
      for (int jl = 0; jl < 2; ++jl)
        acc[il][jl] = MM(AF[il], BF[jl], acc[il][jl]);
    __builtin_amdgcn_s_setprio(0);
    asm volatile("s_waitcnt lgkmcnt(0)" ::: "memory");
    __builtin_amdgcn_sched_barrier(0);
    __builtin_amdgcn_s_setprio(1);
#pragma unroll
    for (int il = 0; il < 4; ++il)
#pragma unroll
      for (int jl = 2; jl < 4; ++jl)
        acc[il][jl] = MM(AF[il], BF[jl], acc[il][jl]);
    __builtin_amdgcn_s_setprio(0);
    asm volatile("s_waitcnt vmcnt(3)" ::: "memory");
    __builtin_amdgcn_s_barrier();
    bf16_t* tmp = cur; cur = nxt; nxt = stg; stg = tmp;
  }

#pragma unroll
  for (int il = 0; il < 4; ++il)
#pragma unroll
    for (int jl = 0; jl < 4; ++jl) {
      const int row0 = m0 + wm + il * 16 + kg * 4;
      const int col = n0 + wn + jl * 16 + r;
      const float sc = (col < qlim) ? scale : 1.0f;
#pragma unroll
      for (int v = 0; v < 4; ++v) {
        float val = acc[il][jl][v] * sc;
        size_t idx = (size_t)(row0 + v) * N + col;
        if (OUT_F32) reinterpret_cast<float*>(C)[idx] = val;
        else reinterpret_cast<unsigned short*>(C)[idx] = f2b_rne(val);
      }
    }
}

// ---------------- V transpose: qkv V-columns [B*S][3072](+2048) -> VT [B*H][64][2048] ----------------
__global__ __launch_bounds__(256) void transpose_v(const bf16_t* __restrict__ qkv,
                                                   bf16_t* __restrict__ vt) {
  __shared__ bf16_t Vs[64 * 72];
  const int t = threadIdx.x;
  const int s0 = blockIdx.x * 64;
  const int bh = blockIdx.y;
  const int b = bh >> 4, h = bh & 15;
  const size_t in_base = ((size_t)b * 2048 + s0) * 3072 + 2048 + h * 64;
#pragma unroll
  for (int c = 0; c < 2; ++c) {
    int chunk = c * 256 + t;
    int ss = chunk >> 3, dd = (chunk & 7) * 8;
    bf16x8 v = *reinterpret_cast<const bf16x8*>(qkv + in_base + (size_t)ss * 3072 + dd);
    *reinterpret_cast<bf16x8*>(Vs + ss * 72 + dd) = v;
  }
  __syncthreads();
  const size_t out_base = (size_t)bh * 64 * 2048 + s0;
#pragma unroll
  for (int c = 0; c < 2; ++c) {
    int chunk = c * 256 + t;
    int dd = chunk >> 3, ss = (chunk & 7) * 8;
    bf16x8 o;
#pragma unroll
    for (int j = 0; j < 8; ++j) o[j] = Vs[(ss + j) * 72 + dd];
    *reinterpret_cast<bf16x8*>(vt + out_base + (size_t)dd * 2048 + ss) = o;
  }
}

// ---------------- causal flash attention: DUAL-CONTEXT shared-KV-stream ----------------
// Block handles q-tiles L=pair and H=15-pair.  L's KV range [0, 2p+2) is a PREFIX of
// H's [0, 32-2p): one staging stream serves both.  Per KV tile the wave runs two
// independent compute streams (QK_L, QK_H, softmax_L, PV_L, softmax_H, PV_H) -> H's
// MFMAs overlap L's softmax VALU and vice versa, filling the ~40% idle issue slots
// the single-context kernel shows.  tmaxL < tmaxH always -> two wave-uniform regions.
// grid (64 bh, 8 pair); XCD = bh%8 (8 heads/XCD = 4 MB K/V = one L2). LDS 70.8 KB ->
// 2 blocks/CU.
__global__ __launch_bounds__(512, 4) void flash_attn(const bf16_t* __restrict__ QKV,
                                                     const bf16_t* __restrict__ VT,
                                                     unsigned short* __restrict__ O,
                                                     int ostride) {
  __shared__ bf16_t Ks[2][64 * 72];
  __shared__ bf16_t Vts[2][64 * 72];
  __shared__ bf16_t Pl[8][2][16 * 68];
  const int tid = threadIdx.x;
  const int lane = tid & 63, wave = tid >> 6;
  const int r = lane & 15, kg = lane >> 4;
  const int bh = blockIdx.x;
  const int pair = blockIdx.y;         // 0..7
  const int b = bh >> 4, h = bh & 15;
  const size_t qkv_row0 = (size_t)b * 2048 * 3072;
  const int qcol = h * 64, kcol = 1024 + h * 64;
  const size_t vt_base = (size_t)bh * 64 * 2048;
  const size_t o_row0 = (size_t)b * 2048 * ostride;
  const int ocol = h * 64;
  const int srr = tid >> 3, scc = (tid & 7) * 8;

  const int q0L = pair * 128, q0H = (15 - pair) * 128;
  const int qrowL = q0L + wave * 16 + r, qrowH = q0H + wave * 16 + r;
  const int tmaxL = (q0L + wave * 16 + 15) >> 6;  // wave's diagonal tile, L
  const int tmaxH = (q0H + wave * 16 + 15) >> 6;  // wave's diagonal tile, H
  const int NT = 32 - 2 * pair;                    // H's tile count (covers L's prefix)

  const size_t qoffL = qkv_row0 + (size_t)qrowL * 3072 + qcol;
  const size_t qoffH = qkv_row0 + (size_t)qrowH * 3072 + qcol;
  bf16x8 qfL0 = *reinterpret_cast<const bf16x8*>(QKV + qoffL + kg * 8);
  bf16x8 qfL1 = *reinterpret_cast<const bf16x8*>(QKV + qoffL + 32 + kg * 8);
  bf16x8 qfH0 = *reinterpret_cast<const bf16x8*>(QKV + qoffH + kg * 8);
  bf16x8 qfH1 = *reinterpret_cast<const bf16x8*>(QKV + qoffH + 32 + kg * 8);

  f32x4 oaccL[4] = {}, oaccH[4] = {};
  float mL = -3e30f, lL = 0.f, mH = -3e30f, lH = 0.f;

  bf16x8 gk = *reinterpret_cast<const bf16x8*>(QKV + qkv_row0 + (size_t)srr * 3072 + kcol + scc);
  bf16x8 gv = *reinterpret_cast<const bf16x8*>(VT + vt_base + (size_t)srr * 2048 + scc);

  for (int t = 0; t < NT; ++t) {
    const int buf = t & 1;
    *reinterpret_cast<bf16x8*>(&Ks[buf][srr * 72 + scc]) = gk;
    *reinterpret_cast<bf16x8*>(&Vts[buf][srr * 72 + scc]) = gv;
    __syncthreads();
    if (t + 1 < NT) {
      const int kv1 = (t + 1) * 64;
      gk = *reinterpret_cast<const bf16x8*>(QKV + qkv_row0 + (size_t)(kv1 + srr) * 3072 + kcol + scc);
      gv = *reinterpret_cast<const bf16x8*>(VT + vt_base + (size_t)srr * 2048 + kv1 + scc);
    }
    if (t > tmaxH) continue;  // (only possible for small waves on the last tiles)

    const int kv0 = t * 64;
    const bool doL = (t <= tmaxL);

    // --- QK for both contexts (one MFMA cluster; streams independent) ---
    float valsL[16], valsH[16];
    __builtin_amdgcn_s_setprio(1);
#pragma unroll
    for (int nt = 0; nt < 4; ++nt) {
      bf16x8 kf0 = *reinterpret_cast<const bf16x8*>(&Ks[buf][(nt * 16 + r) * 72 + kg * 8]);
      bf16x8 kf1 = *reinterpret_cast<const bf16x8*>(&Ks[buf][(nt * 16 + r) * 72 + 32 + kg * 8]);
      f32x4 sH = {};
      sH = MM(kf0, qfH0, sH);
      sH = MM(kf1, qfH1, sH);
#pragma unroll
      for (int v = 0; v < 4; ++v) valsH[nt * 4 + v] = sH[v];
      if (doL) {
        f32x4 sL = {};
        sL = MM(kf0, qfL0, sL);
        sL = MM(kf1, qfL1, sL);
#pragma unroll
        for (int v = 0; v < 4; ++v) valsL[nt * 4 + v] = sL[v];
      }
    }
    __builtin_amdgcn_s_setprio(0);

    // --- L: softmax + PV (VALU here overlaps H's QK completion; PV_L overlaps softmax_H) ---
    if (doL) {
      if (t == tmaxL) {
#pragma unroll
        for (int nt = 0; nt < 4; ++nt)
#pragma unroll
          for (int v = 0; v < 4; ++v)
            if (kv0 + nt * 16 + kg * 4 + v > qrowL) valsL[nt * 4 + v] = -3e30f;
      }
      float a0 = fmaxf(fmaxf(valsL[0], valsL[1]), valsL[2]);
      float a1 = fmaxf(fmaxf(valsL[3], valsL[4]), valsL[5]);
      float a2 = fmaxf(fmaxf(valsL[6], valsL[7]), valsL[8]);
      float a3 = fmaxf(fmaxf(valsL[9], valsL[10]), valsL[11]);
      float a4 = fmaxf(fmaxf(valsL[12], valsL[13]), valsL[14]);
      float pmax = fmaxf(fmaxf(fmaxf(a0, a1), fmaxf(a2, a3)), fmaxf(a4, valsL[15]));
      if (!__all(pmax <= mL + 8.0f)) {
        pmax = fmaxf(pmax, __shfl_xor(pmax, 16));
        pmax = fmaxf(pmax, __shfl_xor(pmax, 32));
        const float m_new = fmaxf(mL, pmax);
        const float alpha = fast_exp2(mL - m_new);
        lL *= alpha;
        f32x4 al;
#pragma unroll
        for (int v = 0; v < 4; ++v) al[v] = __shfl(alpha, kg * 4 + v);
#pragma unroll
        for (int dt = 0; dt < 4; ++dt)
#pragma unroll
          for (int v = 0; v < 4; ++v) oaccL[dt][v] *= al[v];
        mL = m_new;
      }
#pragma unroll
      for (int ii = 0; ii < 16; ++ii) {
        float p = fast_exp2(valsL[ii] - mL);
        valsL[ii] = p;
        lL += p;
      }
#pragma unroll
      for (int nt = 0; nt < 4; ++nt) {
        bf16x4 pb;
#pragma unroll
        for (int v = 0; v < 4; ++v) pb[v] = (bf16_t)valsL[nt * 4 + v];
        *reinterpret_cast<bf16x4*>(&Pl[wave][0][r * 68 + nt * 16 + kg * 4]) = pb;
      }
      bf16x8 pa0 = *reinterpret_cast<const bf16x8*>(&Pl[wave][0][r * 68 + kg * 8]);
      bf16x8 pa1 = *reinterpret_cast<const bf16x8*>(&Pl[wave][0][r * 68 + 32 + kg * 8]);
#pragma unroll
      for (int dt = 0; dt < 4; ++dt) {
        bf16x8 vb0 = *reinterpret_cast<const bf16x8*>(&Vts[buf][(dt * 16 + r) * 72 + kg * 8]);
        bf16x8 vb1 = *reinterpret_cast<const bf16x8*>(&Vts[buf][(dt * 16 + r) * 72 + 32 + kg * 8]);
        oaccL[dt] = MM(pa0, vb0, oaccL[dt]);
        oaccL[dt] = MM(pa1, vb1, oaccL[dt]);
      }
    }

    // --- H: softmax + PV ---
    {
      if (t == tmaxH) {
#pragma unroll
        for (int nt = 0; nt < 4; ++nt)
#pragma unroll
          for (int v = 0; v < 4; ++v)
            if (kv0 + nt * 16 + kg * 4 + v > qrowH) valsH[nt * 4 + v] = -3e30f;
      }
      float a0 = fmaxf(fmaxf(valsH[0], valsH[1]), valsH[2]);
      float a1 = fmaxf(fmaxf(valsH[3], valsH[4]), valsH[5]);
      float a2 = fmaxf(fmaxf(valsH[6], valsH[7]), valsH[8]);
      float a3 = fmaxf(fmaxf(valsH[9], valsH[10]), valsH[11]);
      float a4 = fmaxf(fmaxf(valsH[12], valsH[13]), valsH[14]);
      float pmax = fmaxf(fmaxf(fmaxf(a0, a1), fmaxf(a2, a3)), fmaxf(a4, valsH[15]));
      if (!__all(pmax <= mH + 8.0f)) {
        pmax = fmaxf(pmax, __shfl_xor(pmax, 16));
        pmax = fmaxf(pmax, __shfl_xor(pmax, 32));
        const float m_new = fmaxf(mH, pmax);
        const float alpha = fast_exp2(mH - m_new);
        lH *= alpha;
        f32x4 al;
#pragma unroll
        for (int v = 0; v < 4; ++v) al[v] = __shfl(alpha, kg * 4 + v);
#pragma unroll
        for (int dt = 0; dt < 4; ++dt)
#pragma unroll
          for (int v = 0; v < 4; ++v) oaccH[dt][v] *= al[v];
        mH = m_new;
      }
#pragma unroll
      for (int ii = 0; ii < 16; ++ii) {
        float p = fast_exp2(valsH[ii] - mH);
        valsH[ii] = p;
        lH += p;
      }
#pragma unroll
      for (int nt = 0; nt < 4; ++nt) {
        bf16x4 pb;
#pragma unroll
        for (int v = 0; v < 4; ++v) pb[v] = (bf16_t)valsH[nt * 4 + v];
        *reinterpret_cast<bf16x4*>(&Pl[wave][1][r * 68 + nt * 16 + kg * 4]) = pb;
      }
      bf16x8 pa0 = *reinterpret_cast<const bf16x8*>(&Pl[wave][1][r * 68 + kg * 8]);
      bf16x8 pa1 = *reinterpret_cast<const bf16x8*>(&Pl[wave][1][r * 68 + 32 + kg * 8]);
      __builtin_amdgcn_s_setprio(1);
#pragma unroll
      for (int dt = 0; dt < 4; ++dt) {
        bf16x8 vb0 = *reinterpret_cast<const bf16x8*>(&Vts[buf][(dt * 16 + r) * 72 + kg * 8]);
        bf16x8 vb1 = *reinterpret_cast<const bf16x8*>(&Vts[buf][(dt * 16 + r) * 72 + 32 + kg * 8]);
        oaccH[dt] = MM(pa0, vb0, oaccH[dt]);
        oaccH[dt] = MM(pa1, vb1, oaccH[dt]);
      }
      __builtin_amdgcn_s_setprio(0);
    }
  }

  // --- epilogue: both contexts ---
  {
    float l_row = lL;
    l_row += __shfl_xor(l_row, 16);
    l_row += __shfl_xor(l_row, 32);
    const float linv = 1.0f / l_row;
    f32x4 il;
#pragma unroll
    for (int v = 0; v < 4; ++v) il[v] = __shfl(linv, kg * 4 + v);
    const size_t orow0 = o_row0 + (size_t)(q0L + wave * 16) * ostride + ocol;
#pragma unroll
    for (int dt = 0; dt < 4; ++dt) {
      const int d = dt * 16 + r;
#pragma unroll
      for (int v = 0; v < 4; ++v)
        O[orow0 + (size_t)(kg * 4 + v) * ostride + d] = f2b_rne(oaccL[dt][v] * il[v]);
    }
  }
  {
    float l_row = lH;
    l_row += __shfl_xor(l_row, 16);
    l_row += __shfl_xor(l_row, 32);
    const float linv = 1.0f / l_row;
    f32x4 il;
#pragma unroll
    for (int v = 0; v < 4; ++v) il[v] = __shfl(linv, kg * 4 + v);
    const size_t orow0 = o_row0 + (size_t)(q0H + wave * 16) * ostride + ocol;
#pragma unroll
    for (int dt = 0; dt < 4; ++dt) {
      const int d = dt * 16 + r;
#pragma unroll
      for (int v = 0; v < 4; ++v)
        O[orow0 + (size_t)(kg * 4 + v) * ostride + d] = f2b_rne(oaccH[dt][v] * il[v]);
    }
  }
}

// ---------------- launcher ----------------
extern "C" void kernel_launch(void* const* d_in, const int* in_sizes, int n_in,
                              void* d_out, int out_size, void* d_ws, size_t ws_size,
                              hipStream_t stream) {
  const float* x  = (const float*)d_in[0];
  const float* Wq = (const float*)d_in[1];
  const float* Wk = (const float*)d_in[2];
  const float* Wv = (const float*)d_in[3];
  const float* Wo = (const float*)d_in[4];

  char* ws = (char*)d_ws;
  bf16_t* xb  = (bf16_t*)(ws);
  bf16_t* wqb = (bf16_t*)(ws + (16u << 20));
  bf16_t* wob = (bf16_t*)(ws + (22u << 20));
  bf16_t* qkv = (bf16_t*)(ws + (24u << 20));
  bf16_t* vt  = (bf16_t*)(ws);

  hipFuncSetAttribute(reinterpret_cast<const void*>(&gemmk<0>),
                      hipFuncAttributeMaxDynamicSharedMemorySize, 73728);
  hipFuncSetAttribute(reinterpret_cast<const void*>(&gemmk<1>),
                      hipFuncAttributeMaxDynamicSharedMemorySize, 73728);

  const int NX = 4 * 2048 * 1024;
  cast_f32_bf16<<<NX / 2048, 256, 0, stream>>>(x, (unsigned short*)xb, NX);
  cast_w4<<<dim3(512, 4), 256, 0, stream>>>(Wq, Wk, Wv, Wo, (unsigned short*)wqb);

  // fused QKV projection; Q cols scaled by 1/sqrt(dk)*log2(e) (exp2-domain softmax)
  gemmk<0><<<dim3(3072 / 256, 8192 / 128), 512, 73728, stream>>>(
      xb, wqb, qkv, 8192, 3072, 1024, 1024, 0.18033688011112042f, 1024);

  transpose_v<<<dim3(2048 / 64, 64), 256, 0, stream>>>(qkv, vt);

  flash_attn<<<dim3(64, 8), 512, 0, stream>>>(qkv, vt, (unsigned short*)qkv, 3072);

  gemmk<1><<<dim3(1024 / 256, 8192 / 128), 512, 73728, stream>>>(
      qkv, wob, d_out, 8192, 1024, 1024, 3072, 1.0f, 0);
}